// Round 2
// baseline (83.821 us; speedup 1.0000x reference)
//
#include <hip/hip_runtime.h>

// CrossCompress: B=16384, D=128, fp32.
// item_out[b,:]   = v * (e.w_vv) + e * (v.w_ev) + bias_v
// entity_out[b,:] = v * (e.w_ve) + e * (v.w_ee) + bias_e
//
// Layout v3: 16 lanes per row, 8 floats (2x float4: col and col+64) per lane.
// Butterfly reduce is 4 levels (xor 8,4,2,1), all within 16-aligned lane
// groups -> 2.5x fewer ds_bpermute wave-instructions per row than the
// 32-lane/5-level variant. Each thread processes two independent rows
// (row0 = 32*blk + g, row1 = row0 + 16): 128 B of streaming loads in
// flight per thread, broadcast weights amortized over 2 rows.
// Block = 256 threads = 16 groups -> 32 rows/block; grid = B/32 = 512.

#define BROWS 16384
#define DDIM  128

__device__ __forceinline__ float dot4(const float4 a, const float4 b) {
    return a.x * b.x + a.y * b.y + a.z * b.z + a.w * b.w;
}

__global__ __launch_bounds__(256) void cross_compress_kernel(
    const float* __restrict__ v_in,    // item_embedding   [B,D]
    const float* __restrict__ e_in,    // entity_embedding [B,D]
    const float* __restrict__ w_vv,    // [D]
    const float* __restrict__ w_ve,
    const float* __restrict__ w_ev,
    const float* __restrict__ w_ee,
    const float* __restrict__ bias_v,
    const float* __restrict__ bias_e,
    float* __restrict__ out)           // [2,B,D] flat: item_out then entity_out
{
    const int sub = threadIdx.x & 15;      // lane within 16-lane row group
    const int g   = threadIdx.x >> 4;      // 0..15: row group within block
    const int col = sub * 4;               // chunk a: [col, col+4); chunk b: +64

    const int row0 = blockIdx.x * 32 + g;
    const int row1 = row0 + 16;

    // Streaming loads: 8x float4 = 128 B in flight before any dependent use.
    const float* v0p = v_in + row0 * DDIM + col;
    const float* e0p = e_in + row0 * DDIM + col;
    const float* v1p = v_in + row1 * DDIM + col;
    const float* e1p = e_in + row1 * DDIM + col;
    const float4 v0a = *reinterpret_cast<const float4*>(v0p);
    const float4 v0b = *reinterpret_cast<const float4*>(v0p + 64);
    const float4 e0a = *reinterpret_cast<const float4*>(e0p);
    const float4 e0b = *reinterpret_cast<const float4*>(e0p + 64);
    const float4 v1a = *reinterpret_cast<const float4*>(v1p);
    const float4 v1b = *reinterpret_cast<const float4*>(v1p + 64);
    const float4 e1a = *reinterpret_cast<const float4*>(e1p);
    const float4 e1b = *reinterpret_cast<const float4*>(e1p + 64);

    // Broadcast weights/biases (L1-resident), two chunks each.
    const float4 wvva = *reinterpret_cast<const float4*>(w_vv + col);
    const float4 wvvb = *reinterpret_cast<const float4*>(w_vv + col + 64);
    const float4 wvea = *reinterpret_cast<const float4*>(w_ve + col);
    const float4 wveb = *reinterpret_cast<const float4*>(w_ve + col + 64);
    const float4 weva = *reinterpret_cast<const float4*>(w_ev + col);
    const float4 wevb = *reinterpret_cast<const float4*>(w_ev + col + 64);
    const float4 weea = *reinterpret_cast<const float4*>(w_ee + col);
    const float4 weeb = *reinterpret_cast<const float4*>(w_ee + col + 64);

    // Per-lane partial dots over 8 elements, two independent rows.
    float a_vv = dot4(e0a, wvva) + dot4(e0b, wvvb);   // e0 . w_vv
    float a_ev = dot4(v0a, weva) + dot4(v0b, wevb);   // v0 . w_ev
    float a_ve = dot4(e0a, wvea) + dot4(e0b, wveb);   // e0 . w_ve
    float a_ee = dot4(v0a, weea) + dot4(v0b, weeb);   // v0 . w_ee
    float b_vv = dot4(e1a, wvva) + dot4(e1b, wvvb);
    float b_ev = dot4(v1a, weva) + dot4(v1b, wevb);
    float b_ve = dot4(e1a, wvea) + dot4(e1b, wveb);
    float b_ee = dot4(v1a, weea) + dot4(v1b, weeb);

    // 4-level butterfly within each 16-lane group (xor masks < 16 never
    // leave a 16-aligned group). Eight independent chains overlap.
    #pragma unroll
    for (int off = 8; off >= 1; off >>= 1) {
        a_vv += __shfl_xor(a_vv, off, 64);
        a_ev += __shfl_xor(a_ev, off, 64);
        a_ve += __shfl_xor(a_ve, off, 64);
        a_ee += __shfl_xor(a_ee, off, 64);
        b_vv += __shfl_xor(b_vv, off, 64);
        b_ev += __shfl_xor(b_ev, off, 64);
        b_ve += __shfl_xor(b_ve, off, 64);
        b_ee += __shfl_xor(b_ee, off, 64);
    }

    const float4 bva = *reinterpret_cast<const float4*>(bias_v + col);
    const float4 bvb = *reinterpret_cast<const float4*>(bias_v + col + 64);
    const float4 bea = *reinterpret_cast<const float4*>(bias_e + col);
    const float4 beb = *reinterpret_cast<const float4*>(bias_e + col + 64);

    float4 o;
    float* io0 = out + (size_t)row0 * DDIM + col;
    float* eo0 = out + (size_t)BROWS * DDIM + (size_t)row0 * DDIM + col;
    float* io1 = out + (size_t)row1 * DDIM + col;
    float* eo1 = out + (size_t)BROWS * DDIM + (size_t)row1 * DDIM + col;

    o.x = v0a.x * a_vv + e0a.x * a_ev + bva.x;
    o.y = v0a.y * a_vv + e0a.y * a_ev + bva.y;
    o.z = v0a.z * a_vv + e0a.z * a_ev + bva.z;
    o.w = v0a.w * a_vv + e0a.w * a_ev + bva.w;
    *reinterpret_cast<float4*>(io0) = o;
    o.x = v0b.x * a_vv + e0b.x * a_ev + bvb.x;
    o.y = v0b.y * a_vv + e0b.y * a_ev + bvb.y;
    o.z = v0b.z * a_vv + e0b.z * a_ev + bvb.z;
    o.w = v0b.w * a_vv + e0b.w * a_ev + bvb.w;
    *reinterpret_cast<float4*>(io0 + 64) = o;

    o.x = v0a.x * a_ve + e0a.x * a_ee + bea.x;
    o.y = v0a.y * a_ve + e0a.y * a_ee + bea.y;
    o.z = v0a.z * a_ve + e0a.z * a_ee + bea.z;
    o.w = v0a.w * a_ve + e0a.w * a_ee + bea.w;
    *reinterpret_cast<float4*>(eo0) = o;
    o.x = v0b.x * a_ve + e0b.x * a_ee + beb.x;
    o.y = v0b.y * a_ve + e0b.y * a_ee + beb.y;
    o.z = v0b.z * a_ve + e0b.z * a_ee + beb.z;
    o.w = v0b.w * a_ve + e0b.w * a_ee + beb.w;
    *reinterpret_cast<float4*>(eo0 + 64) = o;

    o.x = v1a.x * b_vv + e1a.x * b_ev + bva.x;
    o.y = v1a.y * b_vv + e1a.y * b_ev + bva.y;
    o.z = v1a.z * b_vv + e1a.z * b_ev + bva.z;
    o.w = v1a.w * b_vv + e1a.w * b_ev + bva.w;
    *reinterpret_cast<float4*>(io1) = o;
    o.x = v1b.x * b_vv + e1b.x * b_ev + bvb.x;
    o.y = v1b.y * b_vv + e1b.y * b_ev + bvb.y;
    o.z = v1b.z * b_vv + e1b.z * b_ev + bvb.z;
    o.w = v1b.w * b_vv + e1b.w * b_ev + bvb.w;
    *reinterpret_cast<float4*>(io1 + 64) = o;

    o.x = v1a.x * b_ve + e1a.x * b_ee + bea.x;
    o.y = v1a.y * b_ve + e1a.y * b_ee + bea.y;
    o.z = v1a.z * b_ve + e1a.z * b_ee + bea.z;
    o.w = v1a.w * b_ve + e1a.w * b_ee + bea.w;
    *reinterpret_cast<float4*>(eo1) = o;
    o.x = v1b.x * b_ve + e1b.x * b_ee + beb.x;
    o.y = v1b.y * b_ve + e1b.y * b_ee + beb.y;
    o.z = v1b.z * b_ve + e1b.z * b_ee + beb.z;
    o.w = v1b.w * b_ve + e1b.w * b_ee + beb.w;
    *reinterpret_cast<float4*>(eo1 + 64) = o;
}

extern "C" void kernel_launch(void* const* d_in, const int* in_sizes, int n_in,
                              void* d_out, int out_size, void* d_ws, size_t ws_size,
                              hipStream_t stream) {
    const float* v_in   = (const float*)d_in[0];
    const float* e_in   = (const float*)d_in[1];
    const float* w_vv   = (const float*)d_in[2];
    const float* w_ve   = (const float*)d_in[3];
    const float* w_ev   = (const float*)d_in[4];
    const float* w_ee   = (const float*)d_in[5];
    const float* bias_v = (const float*)d_in[6];
    const float* bias_e = (const float*)d_in[7];
    float* out = (float*)d_out;

    // 32 rows per 256-thread block
    const int grid = BROWS / 32;   // 512
    cross_compress_kernel<<<grid, 256, 0, stream>>>(
        v_in, e_in, w_vv, w_ve, w_ev, w_ee, bias_v, bias_e, out);
}